// Round 4
// baseline (128.751 us; speedup 1.0000x reference)
//
#include <hip/hip_runtime.h>

#define NPTS 65536
#define NB_SHIFT 16   // log2(NPTS)
#define HID 64

typedef float vfloat4 __attribute__((ext_vector_type(4)));
typedef int   vint4   __attribute__((ext_vector_type(4)));

// ---------------- pre-pass: pos (B,3,N) -> xyzt (B,N) float4 ----------------
__global__ __launch_bounds__(256) void xyzt_kernel(const float* __restrict__ pos,
                                                   vfloat4* __restrict__ xyzt) {
    int g = blockIdx.x * 256 + threadIdx.x;          // 0 .. B*N-1
    int b = g >> NB_SHIFT;
    int n = g & (NPTS - 1);
    const float* p = pos + (size_t)b * 3 * NPTS;
    vfloat4 v;
    v.x = p[n];
    v.y = p[n + NPTS];
    v.z = p[n + 2 * NPTS];
    v.w = 0.f;
    xyzt[((size_t)b << NB_SHIFT) + n] = v;
}

// ---------------- main kernel: 4 threads per point ----------------
// 256 threads handle 64 points; 4096 blocks -> 16384 waves (4x round 3),
// dependent-gather chain per thread is 4 loads (vs 16) -> latency-tolerant
// at the compiler's preferred low VGPR count, no register-pressure fight.
template <int USE_T>
__global__ __launch_bounds__(256, 4) void point_embed_kernel(
    const float*   __restrict__ pos,
    const vfloat4* __restrict__ xyzt,
    const int*     __restrict__ idx,
    const float*   __restrict__ dist,
    const float*   __restrict__ W,
    const float*   __restrict__ bias,
    float*         __restrict__ out) {
    __shared__ float featS[10][64];   // SoA; phase-2 reads broadcast
    const int tid = threadIdx.x;
    const int sub = tid & 3;          // which 4-neighbor slice of the point
    const int pl  = tid >> 2;         // local point 0..63

    // XCD swizzle: XCD k gets a contiguous half-batch -> 1 MB gather window
    const int blk = ((int)blockIdx.x & 7) * 512 + ((int)blockIdx.x >> 3);
    const int g = blk * 64 + pl;      // global point id
    const int b = g >> NB_SHIFT;
    const int n = g & (NPTS - 1);

    // coalesced: consecutive lanes read consecutive int4 / float4
    vint4   iq = ((const vint4*)idx)[(size_t)g * 4 + sub];
    vfloat4 dq = ((const vfloat4*)dist)[(size_t)g * 4 + sub];

    float cx, cy, cz;
    float mxx, mxy, mxz, mnx, mny, mnz;

    if (USE_T) {
        const vfloat4* xb = xyzt + ((size_t)b << NB_SHIFT);
        // 4 independent gathers -> all in flight even at ~40 VGPR
        vfloat4 q0 = xb[(unsigned)iq.x];
        vfloat4 q1 = xb[(unsigned)iq.y];
        vfloat4 q2 = xb[(unsigned)iq.z];
        vfloat4 q3 = xb[(unsigned)iq.w];
        vfloat4 c  = xb[n];           // same addr across the 4 lanes of a point
        cx = c.x; cy = c.y; cz = c.z;
        mxx = fmaxf(fmaxf(q0.x, q1.x), fmaxf(q2.x, q3.x));
        mxy = fmaxf(fmaxf(q0.y, q1.y), fmaxf(q2.y, q3.y));
        mxz = fmaxf(fmaxf(q0.z, q1.z), fmaxf(q2.z, q3.z));
        mnx = fminf(fminf(q0.x, q1.x), fminf(q2.x, q3.x));
        mny = fminf(fminf(q0.y, q1.y), fminf(q2.y, q3.y));
        mnz = fminf(fminf(q0.z, q1.z), fminf(q2.z, q3.z));
    } else {
        const float* px = pos + (size_t)b * 3 * NPTS;
        cx = px[n]; cy = px[n + NPTS]; cz = px[n + 2 * NPTS];
        mxx = mxy = mxz = -INFINITY;
        mnx = mny = mnz = INFINITY;
        int ids[4] = {iq.x, iq.y, iq.z, iq.w};
#pragma unroll
        for (int j = 0; j < 4; ++j) {
            float qx = px[(unsigned)ids[j]];
            float qy = px[(unsigned)ids[j] + NPTS];
            float qz = px[(unsigned)ids[j] + 2 * NPTS];
            mxx = fmaxf(mxx, qx); mxy = fmaxf(mxy, qy); mxz = fmaxf(mxz, qz);
            mnx = fminf(mnx, qx); mny = fminf(mny, qy); mnz = fminf(mnz, qz);
        }
    }
    float md = fmaxf(fmaxf(dq.x, dq.y), fmaxf(dq.z, dq.w));

    // butterfly across the 4 lanes of each point (lanes ^1, ^2)
#pragma unroll
    for (int m = 1; m <= 2; m <<= 1) {
        mxx = fmaxf(mxx, __shfl_xor(mxx, m));
        mxy = fmaxf(mxy, __shfl_xor(mxy, m));
        mxz = fmaxf(mxz, __shfl_xor(mxz, m));
        mnx = fminf(mnx, __shfl_xor(mnx, m));
        mny = fminf(mny, __shfl_xor(mny, m));
        mnz = fminf(mnz, __shfl_xor(mnz, m));
        md  = fmaxf(md,  __shfl_xor(md,  m));
    }

    if (sub == 0) {   // 16 active lanes/wave, 16 consecutive addrs: no conflict
        featS[0][pl] = cx;
        featS[1][pl] = cy;
        featS[2][pl] = cz;
        featS[3][pl] = mxx;
        featS[4][pl] = mxy;
        featS[5][pl] = mxz;
        featS[6][pl] = cx - mnx;
        featS[7][pl] = cy - mny;
        featS[8][pl] = cz - mnz;
        featS[9][pl] = md;
    }

    // W/bias: issued while waiting on the barrier; L2/L3-hot after block 0
    const int hq = tid & 15;
    vfloat4 Wv[10];
#pragma unroll
    for (int c = 0; c < 10; ++c)
        Wv[c] = ((const vfloat4*)(W + c * HID))[hq];
    vfloat4 bv = ((const vfloat4*)bias)[hq];

    __syncthreads();

    // --- phase 2: 64 points x 64 hidden, coalesced nontemporal stores ---
    const int prow = tid >> 4;                       // 0..15
    const size_t outbase = (size_t)blk * 64 * HID;
#pragma unroll
    for (int i = 0; i < 4; ++i) {
        const int p = i * 16 + prow;
        vfloat4 acc = bv;
#pragma unroll
        for (int c = 0; c < 10; ++c) {
            const float fv = featS[c][p];
            acc.x += fv * Wv[c].x;
            acc.y += fv * Wv[c].y;
            acc.z += fv * Wv[c].z;
            acc.w += fv * Wv[c].w;
        }
        acc.x = fmaxf(acc.x, 0.f);
        acc.y = fmaxf(acc.y, 0.f);
        acc.z = fmaxf(acc.z, 0.f);
        acc.w = fmaxf(acc.w, 0.f);
        __builtin_nontemporal_store(
            acc, (vfloat4*)(out + outbase + (size_t)p * HID) + hq);
    }
}

extern "C" void kernel_launch(void* const* d_in, const int* in_sizes, int n_in,
                              void* d_out, int out_size, void* d_ws, size_t ws_size,
                              hipStream_t stream) {
    const float* pos  = (const float*)d_in[0];
    const int*   idx  = (const int*)d_in[1];
    const float* dist = (const float*)d_in[2];
    const float* W    = (const float*)d_in[3];
    const float* bias = (const float*)d_in[4];
    float* out = (float*)d_out;

    const int total = in_sizes[0] / 3;       // B*N = 262144
    const size_t need = (size_t)total * sizeof(vfloat4);  // 16 MB

    if (ws_size >= need) {
        xyzt_kernel<<<total / 256, 256, 0, stream>>>(pos, (vfloat4*)d_ws);
        point_embed_kernel<1><<<total / 64, 256, 0, stream>>>(
            pos, (const vfloat4*)d_ws, idx, dist, W, bias, out);
    } else {
        point_embed_kernel<0><<<total / 64, 256, 0, stream>>>(
            pos, nullptr, idx, dist, W, bias, out);
    }
}